// Round 9
// baseline (22067.354 us; speedup 1.0000x reference)
//
#include <hip/hip_runtime.h>
#include <hip/hip_fp16.h>

// ============================================================================
// 2-layer LSTM with projection (proj_size=128, H=1024, B=64, T=2048)
//
// Round 9 = round 8 RESUBMITTED UNCHANGED (round 8 was an infra flake:
// container died before the kernel was pushed; zero measurement taken).
// Design recap:
//  - 16 WGs/layer x 256 thr (H-slice 64/WG). launch_bounds(256,1): VGPR cap
//    512 (round-6 trap avoided). Wave wv owns unit-group wv (units wv*16..+16),
//    all 4 M-tiles, gate N-tiles {g*4+wv} -> elementwise stays lane-local.
//  - Atomic-add h-accumulation (round-7 scheme, halved contention: 16 RMW
//    per line instead of 32). 8-deep slot ring, zero slot t+4 during step t.
//  - Counters replaced by per-WG FLAG STORES (round-5-proven): 16 dwords in
//    one 64B line per layer, polled with one 16-lane load. No fetch-add
//    serialization on a hot line.
//  - l0's x-part of the gate GEMM (K=128..255, 64 MFMAs) runs BEFORE the
//    poll (input data, recurrence-independent) -> off the serial chain.
//  - All cross-WG data via relaxed AGENT atomics (sc1, MALL-coherent, no
//    cache maintenance). Timeout + canary kept.
// Throttles: l0 step t waits own flags0>=t, flags1>=t-3 (ring reuse);
//            l1 step t waits flags0>=t+1 (h1_t complete), own flags1>=t.
// ============================================================================

typedef _Float16 f16;
typedef _Float16 f16x4 __attribute__((ext_vector_type(4)));
typedef _Float16 f16x8 __attribute__((ext_vector_type(8)));
typedef float f32x4 __attribute__((ext_vector_type(4)));
typedef unsigned long long u64;
struct U128 { u64 lo, hi; };

#define TSTEPS 2048
#define NWG 16
#define TIMEOUT_TICKS 200000000ull   // ~2 s at 100 MHz s_memrealtime

// ---- workspace layout (bytes) ----
#define BSW_OFF  0ull
#define BSW_SZ   (32ull*65536ull*2ull)        // gate weights, 4 MiB
#define WHR_OFF  (BSW_OFF + BSW_SZ)
#define WHR_SZ   (32ull*8192ull*2ull)         // proj weights, 512 KiB
#define BIAS_OFF (WHR_OFF + WHR_SZ)
#define BIAS_SZ  (2ull*16ull*256ull*4ull)
#define HACC_OFF (BIAS_OFF + BIAS_SZ)
#define HACC_SZ  (2ull*8ull*8192ull*4ull)     // [lyr][slot8][64b x 128p] f32
#define FLAG_OFF (HACC_OFF + HACC_SZ)
#define FLAG_SZ  (256ull)                     // flags0[16] @0, flags1[16] @64B
#define WS_NEED  (FLAG_OFF + FLAG_SZ)

__device__ __forceinline__ float sigm(float v) {
  float e = __builtin_amdgcn_exp2f(-1.4426950408889634f * v);
  return __builtin_amdgcn_rcpf(1.0f + e);
}
__device__ __forceinline__ float tanh_(float v) {
  float a = fabsf(v);
  float e = __builtin_amdgcn_exp2f(-2.8853900817779268f * a);
  float r = (1.0f - e) * __builtin_amdgcn_rcpf(1.0f + e);
  return copysignf(r, v);
}

// ---- relaxed agent-scope atomic helpers (compile to global_* sc1) --------
__device__ __forceinline__ u64 ald64(const void* p) {
  return __hip_atomic_load((const u64*)p, __ATOMIC_RELAXED, __HIP_MEMORY_SCOPE_AGENT);
}
__device__ __forceinline__ unsigned ald32u(const unsigned* p) {
  return __hip_atomic_load(p, __ATOMIC_RELAXED, __HIP_MEMORY_SCOPE_AGENT);
}
__device__ __forceinline__ void ast32f(float* p, float v) {
  __hip_atomic_store((unsigned*)p, __builtin_bit_cast(unsigned, v),
                     __ATOMIC_RELAXED, __HIP_MEMORY_SCOPE_AGENT);
}
__device__ __forceinline__ void ast32u(unsigned* p, unsigned v) {
  __hip_atomic_store(p, v, __ATOMIC_RELAXED, __HIP_MEMORY_SCOPE_AGENT);
}
__device__ __forceinline__ f32x4 ald_f32x4(const float* p) {
  U128 u; u.lo = ald64(p); u.hi = ald64(p + 2);
  return __builtin_bit_cast(f32x4, u);
}
__device__ __forceinline__ void aadd_f32(float* p, float v) {
  (void)__hip_atomic_fetch_add(p, v, __ATOMIC_RELAXED, __HIP_MEMORY_SCOPE_AGENT);
}
__device__ __forceinline__ void vm_drain() {
  asm volatile("s_waitcnt vmcnt(0)" ::: "memory");
}

// ---------------------------------------------------------------------------
// Setup. Fragment conventions (16x16x32):
//   A-frag: lane l holds A[m=l&15][k=(l>>4)*8+i]
//   B-frag: lane l holds B[k=(l>>4)*8+i][n=l&15]
//   D:      lane l, reg r -> D[m=(l>>4)*4+r][n=l&15]
// Gate rows local: rl = gate*64 + u (u in [0,64)); N-tile n = gate*4+ugroup.
// ---------------------------------------------------------------------------
__global__ void lstm_setup(
    const float* __restrict__ Wih0, const float* __restrict__ Whh0,
    const float* __restrict__ bih0, const float* __restrict__ bhh0,
    const float* __restrict__ Whr0,
    const float* __restrict__ Wih1, const float* __restrict__ Whh1,
    const float* __restrict__ bih1, const float* __restrict__ bhh1,
    const float* __restrict__ Whr1,
    f16* __restrict__ Bsw, f16* __restrict__ Whrsw, float* __restrict__ bias,
    float* __restrict__ hacc, unsigned* __restrict__ flags)
{
  const int blk = blockIdx.x, tid = threadIdx.x;
  if (blk < 32) {
    // gate weights: Bsw[wg][ks8][n16][lane][i]
    const int lyr = blk >> 4, w = blk & 15;
    const float* Whh = lyr ? Whh1 : Whh0;
    const float* Wih = lyr ? Wih1 : Wih0;
    f16* dst = Bsw + (size_t)blk * 65536;
    for (int e = tid; e < 65536; e += 256) {
      int i = e & 7, l = (e >> 3) & 63, n = (e >> 9) & 15, ks = e >> 13;
      int k    = ks * 32 + (l >> 4) * 8 + i;
      int gate = n >> 2, u = (n & 3) * 16 + (l & 15);
      int grow = gate * 1024 + w * 64 + u;
      float v = (k < 128) ? Whh[grow * 128 + k] : Wih[grow * 128 + (k - 128)];
      dst[e] = (f16)v;
    }
  } else if (blk < 64) {
    // proj weights: Whrsw[wg][pt8][ks2][lane][i]: B[kl][p] = Whr[p][w*64+kl]
    const int q = blk - 32, lyr = q >> 4, w = q & 15;
    const float* Whr = lyr ? Whr1 : Whr0;
    f16* dst = Whrsw + (size_t)q * 8192;
    for (int e = tid; e < 8192; e += 256) {
      int i = e & 7, l = (e >> 3) & 63, ks2 = (e >> 9) & 1, pt = e >> 10;
      int p  = pt * 16 + (l & 15);
      int kl = ks2 * 32 + (l >> 4) * 8 + i;
      dst[e] = (f16)Whr[p * 1024 + w * 64 + kl];
    }
  } else if (blk == 64) {
    // bias[lyr][w][rl], rl = gate*64 + u
    for (int e = tid; e < 8192; e += 256) {
      int lyr = e >> 12, w = (e >> 8) & 15, rl = e & 255;
      int grow = (rl >> 6) * 1024 + w * 64 + (rl & 63);
      bias[e] = lyr ? (bih1[grow] + bhh1[grow]) : (bih0[grow] + bhh0[grow]);
    }
  } else {
    for (int e = tid; e < 2 * 8 * 8192; e += 256) ast32f(hacc + e, 0.f);
    if (tid < 32) ast32u(flags + tid, 0u);
  }
}

// ---------------------------------------------------------------------------
// Main persistent kernel: 32 WGs x 256 thr (4 waves).
// ---------------------------------------------------------------------------
__global__ __launch_bounds__(256, 1) void lstm_main(
    const float* __restrict__ x, float* __restrict__ out,
    const f16* __restrict__ Bsw, const f16* __restrict__ Whrsw,
    const float* __restrict__ bias, float* __restrict__ hacc,
    unsigned* __restrict__ flags)
{
  const int tid = threadIdx.x;
  const int lane = tid & 63, wv = tid >> 6;
  const int l15 = lane & 15, lg = lane >> 4;
  const int w = blockIdx.x & 15, lyr = blockIdx.x >> 4;

  const u64 tstart = __builtin_amdgcn_s_memrealtime();
  bool tmo = false;

  __shared__ __align__(16) f16 h_lds[64][136];   // h_{t-1}, row=batch, col=p
  __shared__ __align__(16) f16 x1_lds[64][136];  // l1: h1_t
  __shared__ __align__(16) f16 s_lds[64][72];    // s, row=batch, col=u (64)
  __shared__ int s_go;
  if (tid == 0) s_go = 0;

  // ---- register-resident weights ----
  f16x8 bf[8][4];   // [ks][gate]; N-tile = gate*4 + wv
  {
    const f16* bsl = Bsw + (size_t)(lyr * NWG + w) * 65536;
#pragma unroll
    for (int ks = 0; ks < 8; ++ks)
#pragma unroll
      for (int g = 0; g < 4; ++g)
        bf[ks][g] = *(const f16x8*)(bsl + (((ks * 16 + g * 4 + wv) * 64 + lane) * 8));
  }
  f16x8 wf[2][2];   // [pt][ks2]; P-tile = wv + pt*4
  {
    const f16* wsl = Whrsw + (size_t)(lyr * NWG + w) * 8192;
#pragma unroll
    for (int pt = 0; pt < 2; ++pt)
#pragma unroll
      for (int ks2 = 0; ks2 < 2; ++ks2)
        wf[pt][ks2] = *(const f16x8*)(wsl + ((((wv + pt * 4) * 2 + ks2) * 64 + lane) * 8));
  }
  float bias_r[4];
#pragma unroll
  for (int g = 0; g < 4; ++g)
    bias_r[g] = bias[(lyr * 16 + w) * 256 + g * 64 + wv * 16 + l15];

  float c[4][4] = {{0,0,0,0},{0,0,0,0},{0,0,0,0},{0,0,0,0}};  // [mtl][r]

  unsigned* f0 = flags;
  unsigned* f1 = flags + 16;
  float* myacc = hacc + (size_t)lyr * 8 * 8192;
  float* h1a   = hacc;
  __syncthreads();

  for (int t = 0; t <= TSTEPS; ++t) {
    if (lyr == 0 && t == TSTEPS) break;
    const bool tail = (t == TSTEPS);             // l1 only

    // ---- pre-poll: bias init + (l0) x-part of gate GEMM (K=128..255) ----
    f32x4 acc[4][4];
#pragma unroll
    for (int mtl = 0; mtl < 4; ++mtl)
#pragma unroll
      for (int g = 0; g < 4; ++g) {
        f32x4 b4 = {bias_r[g], bias_r[g], bias_r[g], bias_r[g]};
        acc[mtl][g] = b4;
      }
    if (lyr == 0) {
#pragma unroll
      for (int mtl = 0; mtl < 4; ++mtl) {
        const float* xp = x + ((size_t)(mtl * 16 + l15) * TSTEPS + t) * 128 + lg * 8;
#pragma unroll
        for (int ks2 = 0; ks2 < 4; ++ks2) {
          f32x4 v0 = *(const f32x4*)(xp + ks2 * 32);
          f32x4 v1 = *(const f32x4*)(xp + ks2 * 32 + 4);
          f16x8 hx;
          hx[0]=(f16)v0[0]; hx[1]=(f16)v0[1]; hx[2]=(f16)v0[2]; hx[3]=(f16)v0[3];
          hx[4]=(f16)v1[0]; hx[5]=(f16)v1[1]; hx[6]=(f16)v1[2]; hx[7]=(f16)v1[3];
#pragma unroll
          for (int g = 0; g < 4; ++g)
            acc[mtl][g] = __builtin_amdgcn_mfma_f32_16x16x32_f16(hx, bf[4 + ks2][g], acc[mtl][g], 0, 0, 0);
        }
      }
    }

    // ================= poll flags (wave 0; LDS token for others) ===========
    if (wv == 0) {
      for (;;) {
        bool ok = true;
        if (lane < 16) {
          ok = ald32u((lyr ? f1 : f0) + lane) >= (unsigned)t;        // own layer
        } else if (lane < 32) {
          if (lyr == 0) ok = (t < 4) || (ald32u(f1 + lane - 16) >= (unsigned)(t - 3));
          else          ok = tail || (ald32u(f0 + lane - 16) >= (unsigned)(t + 1));
        }
        if ((__builtin_amdgcn_s_memrealtime() - tstart) > TIMEOUT_TICKS) { ok = true; tmo = true; }
        if (__all(ok)) break;
        __builtin_amdgcn_s_sleep(1);
      }
      __atomic_store_n(&s_go, t + 1, __ATOMIC_RELAXED);
    } else {
      while (__atomic_load_n(&s_go, __ATOMIC_RELAXED) < t + 1)
        __builtin_amdgcn_s_sleep(1);
    }
    asm volatile("" ::: "memory");

    // ================= read: h_{t-1} (+ h1_t for l1), out, zero ============
    {
      const int b = tid >> 2, pb = (tid & 3) * 32;       // 32 f32 per thread
      const float* hp = myacc + (size_t)((t + 7) & 7) * 8192 + b * 128 + pb;
      f32x4 hv4[8];
#pragma unroll
      for (int k = 0; k < 8; ++k) hv4[k] = ald_f32x4(hp + k * 4);
      // out rows from h2_{t-1}; WG w owns p-slice [8w, 8w+8)
      if (lyr == 1 && t >= TSTEPS - 63 && (tid & 3) == (w >> 2)) {
        const int k0 = (w & 3) * 2;
        float* op = out + (size_t)b * 8192 + (t - 1 - (TSTEPS - 64)) * 128 + 8 * w;
        *(f32x4*)op = hv4[k0];
        *(f32x4*)(op + 4) = hv4[k0 + 1];
      }
#pragma unroll
      for (int k = 0; k < 8; ++k) {
        f16x4 h16;
#pragma unroll
        for (int e = 0; e < 4; ++e) h16[e] = (f16)hv4[k][e];
        *(f16x4*)(&h_lds[b][pb + k * 4]) = h16;
      }
      if (lyr == 1 && !tail) {
        const float* xp1 = h1a + (size_t)(t & 7) * 8192 + b * 128 + pb;
#pragma unroll
        for (int k = 0; k < 8; ++k) {
          f32x4 v = ald_f32x4(xp1 + k * 4);
          f16x4 h16;
#pragma unroll
          for (int e = 0; e < 4; ++e) h16[e] = (f16)v[e];
          *(f16x4*)(&x1_lds[b][pb + k * 4]) = h16;
        }
      }
      // zero our p-slice [8w,8w+8) of slot t+4 (holds h[t-4]; reads done)
      if (!tail) {
        float* z = myacc + (size_t)((t + 4) & 7) * 8192 + b * 128 + 8 * w + (tid & 3) * 2;
        ast32f(z, 0.f);
        ast32f(z + 1, 0.f);
      }
    }
    if (tail) break;   // uniform for all l1 threads
    __syncthreads();

    // ================= gates: recurrent part (+ l1 input part) =============
#pragma unroll
    for (int mtl = 0; mtl < 4; ++mtl) {
#pragma unroll
      for (int ks = 0; ks < 4; ++ks) {
        f16x8 af = *(const f16x8*)(&h_lds[mtl * 16 + l15][ks * 32 + lg * 8]);
#pragma unroll
        for (int g = 0; g < 4; ++g)
          acc[mtl][g] = __builtin_amdgcn_mfma_f32_16x16x32_f16(af, bf[ks][g], acc[mtl][g], 0, 0, 0);
      }
      if (lyr == 1) {
#pragma unroll
        for (int ks2 = 0; ks2 < 4; ++ks2) {
          f16x8 xf = *(const f16x8*)(&x1_lds[mtl * 16 + l15][ks2 * 32 + lg * 8]);
#pragma unroll
          for (int g = 0; g < 4; ++g)
            acc[mtl][g] = __builtin_amdgcn_mfma_f32_16x16x32_f16(xf, bf[4 + ks2][g], acc[mtl][g], 0, 0, 0);
        }
      }
      // elementwise: unit = wv*16+l15, batch = mtl*16+lg*4+r
#pragma unroll
      for (int r = 0; r < 4; ++r) {
        float gi = acc[mtl][0][r], gf = acc[mtl][1][r];
        float gg = acc[mtl][2][r], go = acc[mtl][3][r];
        float cc = sigm(gf) * c[mtl][r] + sigm(gi) * tanh_(gg);
        c[mtl][r] = cc;
        float s = sigm(go) * tanh_(cc);
        s_lds[mtl * 16 + lg * 4 + r][wv * 16 + l15] = (f16)s;
      }
    }
    __syncthreads();

    // ================= proj [64,64]x[64,128] + atomic-add accumulate =======
    {
      float* dst = myacc + (size_t)(t & 7) * 8192;
#pragma unroll
      for (int mtl = 0; mtl < 4; ++mtl) {
        f16x8 ap0 = *(const f16x8*)(&s_lds[mtl * 16 + l15][lg * 8]);
        f16x8 ap1 = *(const f16x8*)(&s_lds[mtl * 16 + l15][32 + lg * 8]);
#pragma unroll
        for (int pt = 0; pt < 2; ++pt) {
          f32x4 z = {0.f, 0.f, 0.f, 0.f};
          f32x4 pa = __builtin_amdgcn_mfma_f32_16x16x32_f16(ap0, wf[pt][0], z, 0, 0, 0);
          pa = __builtin_amdgcn_mfma_f32_16x16x32_f16(ap1, wf[pt][1], pa, 0, 0, 0);
          const int p = (wv + pt * 4) * 16 + l15;
#pragma unroll
          for (int r = 0; r < 4; ++r)
            aadd_f32(dst + (mtl * 16 + lg * 4 + r) * 128 + p, pa[r]);
        }
      }
    }
    vm_drain();        // adds + zero stores acked
    __syncthreads();   // all waves drained
    if (tid == 0) ast32u((lyr ? f1 : f0) + w, (unsigned)(t + 1));
  }

  if (tmo && tid == 0) out[0] = 12345.0f;  // livelock canary
}

extern "C" void kernel_launch(void* const* d_in, const int* in_sizes, int n_in,
                              void* d_out, int out_size, void* d_ws, size_t ws_size,
                              hipStream_t stream)
{
  const float* x    = (const float*)d_in[0];
  const float* Wih0 = (const float*)d_in[1];
  const float* Whh0 = (const float*)d_in[2];
  const float* bih0 = (const float*)d_in[3];
  const float* bhh0 = (const float*)d_in[4];
  const float* Whr0 = (const float*)d_in[5];
  const float* Wih1 = (const float*)d_in[6];
  const float* Whh1 = (const float*)d_in[7];
  const float* bih1 = (const float*)d_in[8];
  const float* bhh1 = (const float*)d_in[9];
  const float* Whr1 = (const float*)d_in[10];

  if (ws_size < WS_NEED) return;

  char* ws = (char*)d_ws;
  f16*      Bsw   = (f16*)(ws + BSW_OFF);
  f16*      Whrsw = (f16*)(ws + WHR_OFF);
  float*    bias  = (float*)(ws + BIAS_OFF);
  float*    hacc  = (float*)(ws + HACC_OFF);
  unsigned* flags = (unsigned*)(ws + FLAG_OFF);

  lstm_setup<<<66, 256, 0, stream>>>(Wih0, Whh0, bih0, bhh0, Whr0,
                                     Wih1, Whh1, bih1, bhh1, Whr1,
                                     Bsw, Whrsw, bias, hacc, flags);
  lstm_main<<<32, 256, 0, stream>>>(x, (float*)d_out, Bsw, Whrsw, bias,
                                    hacc, flags);
}

// Round 12
// 17207.138 us; speedup vs baseline: 1.2825x; 1.2825x over previous
//
#include <hip/hip_runtime.h>
#include <hip/hip_fp16.h>

// ============================================================================
// 2-layer LSTM with projection (proj_size=128, H=1024, B=64, T=2048)
//
// Round 12 = round 10 RESUBMITTED UNCHANGED, third attempt (rounds 10 & 11
// were infra flakes: container died before the kernel was pushed).
// Design recap (round 7 base, 8.7 us/step, + serial-chain cuts):
//  - 32 WGs/layer x 256 thr, H-slice 32/WG (r7 geometry; r9 proved halving
//    WGs doubles chain compute for no sync gain).
//  - Flags: per-WG dword STORES (flags0[32], flags1[32]) instead of fetch-add
//    counters -- no RMW serialization; poll = one 32-lane load.
//  - ALL 4 waves poll independently (LDS go-token hop deleted).
//  - l0's x-part of the gate GEMM (K=128..255, 32 MFMAs/wave) hoisted BEFORE
//    the poll. Read phase issues all h2/h1 loads before any convert.
//  - Atomic-add h-accumulation into 8-deep slot ring (r7 scheme unchanged;
//    r9 showed 32-deep RMW chains are NOT the bottleneck). Zero slot t+4
//    during step t (flag-ordered; audited r8/r9/r11/r12 incl. t<4 warm-up).
//  - All cross-WG data via relaxed AGENT atomics (sc1, MALL-coherent, no
//    cache maintenance, zero multi-output asm). Timeout + canary kept.
// Throttles: l0 step t: own f0>=t, f1>=t-3 (slot reuse). l1 step t:
//            f0>=t+1 (h1_t complete), own f1>=t.
// ============================================================================

typedef _Float16 f16;
typedef _Float16 f16x4 __attribute__((ext_vector_type(4)));
typedef _Float16 f16x8 __attribute__((ext_vector_type(8)));
typedef float f32x4 __attribute__((ext_vector_type(4)));
typedef unsigned long long u64;
struct U128 { u64 lo, hi; };

#define TSTEPS 2048
#define NW 32
#define TIMEOUT_TICKS 200000000ull   // ~2 s at 100 MHz s_memrealtime

// ---- workspace layout (bytes) ----
#define BSW_OFF  0ull
#define BSW_SZ   (64ull*32768ull*2ull)        // gate weights, 4 MiB
#define WHR_OFF  (BSW_OFF + BSW_SZ)
#define WHR_SZ   (64ull*4096ull*2ull)         // proj weights, 512 KiB
#define BIAS_OFF (WHR_OFF + WHR_SZ)
#define BIAS_SZ  (8192ull*4ull)
#define HACC_OFF (BIAS_OFF + BIAS_SZ)
#define HACC_SZ  (2ull*8ull*8192ull*4ull)     // [lyr][slot8][64b x 128p] f32
#define FLAG_OFF (HACC_OFF + HACC_SZ)
#define FLAG_SZ  (512ull)                     // f0[32] @0, f1[32] @128B
#define WS_NEED  (FLAG_OFF + FLAG_SZ)

__device__ __forceinline__ float sigm(float v) {
  float e = __builtin_amdgcn_exp2f(-1.4426950408889634f * v);
  return __builtin_amdgcn_rcpf(1.0f + e);
}
__device__ __forceinline__ float tanh_(float v) {
  float a = fabsf(v);
  float e = __builtin_amdgcn_exp2f(-2.8853900817779268f * a);
  float r = (1.0f - e) * __builtin_amdgcn_rcpf(1.0f + e);
  return copysignf(r, v);
}

// ---- relaxed agent-scope atomic helpers (compile to global_* sc1) --------
__device__ __forceinline__ u64 ald64(const void* p) {
  return __hip_atomic_load((const u64*)p, __ATOMIC_RELAXED, __HIP_MEMORY_SCOPE_AGENT);
}
__device__ __forceinline__ unsigned ald32u(const unsigned* p) {
  return __hip_atomic_load(p, __ATOMIC_RELAXED, __HIP_MEMORY_SCOPE_AGENT);
}
__device__ __forceinline__ void ast32f(float* p, float v) {
  __hip_atomic_store((unsigned*)p, __builtin_bit_cast(unsigned, v),
                     __ATOMIC_RELAXED, __HIP_MEMORY_SCOPE_AGENT);
}
__device__ __forceinline__ void ast32u(unsigned* p, unsigned v) {
  __hip_atomic_store(p, v, __ATOMIC_RELAXED, __HIP_MEMORY_SCOPE_AGENT);
}
__device__ __forceinline__ f32x4 ald_f32x4(const float* p) {
  U128 u; u.lo = ald64(p); u.hi = ald64(p + 2);
  return __builtin_bit_cast(f32x4, u);
}
__device__ __forceinline__ void aadd_f32(float* p, float v) {
  (void)__hip_atomic_fetch_add(p, v, __ATOMIC_RELAXED, __HIP_MEMORY_SCOPE_AGENT);
}
__device__ __forceinline__ void vm_drain() {
  asm volatile("s_waitcnt vmcnt(0)" ::: "memory");
}

// ---------------------------------------------------------------------------
// Setup (round-7 weight packing, proven). Fragment conventions (16x16x32):
//   A-frag: lane l holds A[m=l&15][k=(l>>4)*8+i]
//   B-frag: lane l holds B[k=(l>>4)*8+i][n=l&15]
//   D:      lane l, reg r -> D[m=(l>>4)*4+r][n=l&15]
// ---------------------------------------------------------------------------
__global__ void lstm_setup(
    const float* __restrict__ Wih0, const float* __restrict__ Whh0,
    const float* __restrict__ bih0, const float* __restrict__ bhh0,
    const float* __restrict__ Whr0,
    const float* __restrict__ Wih1, const float* __restrict__ Whh1,
    const float* __restrict__ bih1, const float* __restrict__ bhh1,
    const float* __restrict__ Whr1,
    f16* __restrict__ Bsw, f16* __restrict__ Whrsw, float* __restrict__ bias,
    float* __restrict__ hacc, unsigned* __restrict__ flags)
{
  const int blk = blockIdx.x, tid = threadIdx.x;
  if (blk < 64) {
    const int lyr = blk >> 5, w = blk & 31;
    const float* Whh = lyr ? Whh1 : Whh0;
    const float* Wih = lyr ? Wih1 : Wih0;
    f16* dst = Bsw + (size_t)blk * 32768;
    for (int e = tid; e < 32768; e += 256) {
      int i = e & 7, l = (e >> 3) & 63, ntG = (e >> 9) & 7, ks = e >> 12;
      int k  = ks * 32 + (l >> 4) * 8 + i;
      int rl = ntG * 16 + (l & 15);
      int grow = (rl >> 5) * 1024 + w * 32 + (rl & 31);
      float v = (k < 128) ? Whh[grow * 128 + k] : Wih[grow * 128 + (k - 128)];
      dst[e] = (f16)v;
    }
  } else if (blk < 128) {
    const int q = blk - 64, lyr = q >> 5, w = q & 31;
    const float* Whr = lyr ? Whr1 : Whr0;
    f16* dst = Whrsw + (size_t)q * 4096;
    for (int e = tid; e < 4096; e += 256) {
      int i = e & 7, l = (e >> 3) & 63, pnG = e >> 9;
      int p = pnG * 16 + (l & 15);
      int hg = w * 32 + (l >> 4) * 8 + i;
      dst[e] = (f16)Whr[p * 1024 + hg];
    }
  } else if (blk == 128) {
    for (int e = tid; e < 8192; e += 256) {
      int lyr = e >> 12, j = e & 4095;
      bias[e] = lyr ? (bih1[j] + bhh1[j]) : (bih0[j] + bhh0[j]);
    }
  } else {
    for (int e = tid; e < 2 * 8 * 8192; e += 256) ast32f(hacc + e, 0.f);
    if (tid < 128) ast32u(flags + tid, 0u);
  }
}

// ---------------------------------------------------------------------------
// Main persistent kernel: 64 WGs x 256 thr (4 waves, (wy,wx) 2x2; r7 wave
// mapping: gate M-tiles {wy*2,wy*2+1}, gate N-tiles {ntl*2+wx} (ntl = gate
// type); proj P-tiles {pnl*2+wx}).
// ---------------------------------------------------------------------------
__global__ __launch_bounds__(256, 1) void lstm_main(
    const float* __restrict__ x, float* __restrict__ out,
    const f16* __restrict__ Bsw, const f16* __restrict__ Whrsw,
    const float* __restrict__ bias, float* __restrict__ hacc,
    unsigned* __restrict__ flags)
{
  const int tid = threadIdx.x;
  const int lane = tid & 63, wv = tid >> 6;
  const int wy = wv >> 1, wx = wv & 1;
  const int l15 = lane & 15, lg = lane >> 4;
  const int w = blockIdx.x & 31, lyr = blockIdx.x >> 5;

  const u64 tstart = __builtin_amdgcn_s_memrealtime();
  bool tmo = false;

  __shared__ __align__(16) f16 h_lds[64][136];   // h_{t-1}, row=batch, col=p
  __shared__ __align__(16) f16 x1_lds[64][136];  // l1: h1_t
  __shared__ __align__(16) f16 s_lds[64][40];    // s, row=batch, 32 cols used

  // ---- register-resident weights (r7 packing) ----
  f16x8 bf[8][4];
  {
    const f16* bsl = Bsw + (size_t)(lyr * NW + w) * 32768;
#pragma unroll
    for (int ks = 0; ks < 8; ++ks)
#pragma unroll
      for (int ntl = 0; ntl < 4; ++ntl)
        bf[ks][ntl] = *(const f16x8*)(bsl + (((ks * 8 + (ntl * 2 + wx)) * 64 + lane) * 8));
  }
  f16x8 wf[4];
  {
    const f16* wsl = Whrsw + (size_t)(lyr * NW + w) * 4096;
#pragma unroll
    for (int pnl = 0; pnl < 4; ++pnl)
      wf[pnl] = *(const f16x8*)(wsl + (((pnl * 2 + wx) * 64 + lane) * 8));
  }
  float bias_r[4];
#pragma unroll
  for (int ntl = 0; ntl < 4; ++ntl)
    bias_r[ntl] = bias[lyr * 4096 + ntl * 1024 + w * 32 + wx * 16 + l15];

  float c[2][4] = {{0.f,0.f,0.f,0.f},{0.f,0.f,0.f,0.f}};

  unsigned* f0 = flags;        // [32]
  unsigned* f1 = flags + 32;   // [32]
  unsigned* myf = lyr ? f1 : f0;
  float* myacc = hacc + (size_t)lyr * 8 * 8192;
  float* h1a   = hacc;
  __syncthreads();

  for (int t = 0; t <= TSTEPS; ++t) {
    if (lyr == 0 && t == TSTEPS) break;
    const bool tail = (t == TSTEPS);             // l1 only

    // ---- pre-poll: bias init + (l0) x-part of gate GEMM (K=128..255) ------
    f32x4 acc[2][4];
#pragma unroll
    for (int mtl = 0; mtl < 2; ++mtl)
#pragma unroll
      for (int ntl = 0; ntl < 4; ++ntl) {
        f32x4 b4 = {bias_r[ntl], bias_r[ntl], bias_r[ntl], bias_r[ntl]};
        acc[mtl][ntl] = b4;
      }
    if (lyr == 0) {
#pragma unroll
      for (int mtl = 0; mtl < 2; ++mtl) {
        const float* xp = x + ((size_t)((wy * 2 + mtl) * 16 + l15) * TSTEPS + t) * 128 + lg * 8;
#pragma unroll
        for (int ks2 = 0; ks2 < 4; ++ks2) {
          f32x4 v0 = *(const f32x4*)(xp + ks2 * 32);
          f32x4 v1 = *(const f32x4*)(xp + ks2 * 32 + 4);
          f16x8 hx;
          hx[0]=(f16)v0[0]; hx[1]=(f16)v0[1]; hx[2]=(f16)v0[2]; hx[3]=(f16)v0[3];
          hx[4]=(f16)v1[0]; hx[5]=(f16)v1[1]; hx[6]=(f16)v1[2]; hx[7]=(f16)v1[3];
#pragma unroll
          for (int ntl = 0; ntl < 4; ++ntl)
            acc[mtl][ntl] = __builtin_amdgcn_mfma_f32_16x16x32_f16(hx, bf[4 + ks2][ntl], acc[mtl][ntl], 0, 0, 0);
        }
      }
    }

    // ================= poll: ALL waves independently (no token hop) ========
    for (;;) {
      bool ok = true;
      if (lane < 32) {
        ok = ald32u(myf + lane) >= (unsigned)t;                       // own layer
      } else {
        const int l2 = lane - 32;
        if (lyr == 0) ok = (t < 4) || (ald32u(f1 + l2) >= (unsigned)(t - 3));
        else          ok = tail || (ald32u(f0 + l2) >= (unsigned)(t + 1));
      }
      if ((__builtin_amdgcn_s_memrealtime() - tstart) > TIMEOUT_TICKS) { ok = true; tmo = true; }
      if (__all(ok)) break;
      __builtin_amdgcn_s_sleep(1);
    }
    asm volatile("" ::: "memory");

    // ================= read: issue ALL loads, then convert =================
    {
      const int b = tid >> 2, pb = (tid & 3) * 32;       // 32 f32 per thread
      const float* hp = myacc + (size_t)((t + 7) & 7) * 8192 + b * 128 + pb;
      f32x4 hv4[8];
#pragma unroll
      for (int k = 0; k < 8; ++k) hv4[k] = ald_f32x4(hp + k * 4);
      f32x4 x1v[8];
      if (lyr == 1 && !tail) {
        const float* xp1 = h1a + (size_t)(t & 7) * 8192 + b * 128 + pb;
#pragma unroll
        for (int k = 0; k < 8; ++k) x1v[k] = ald_f32x4(xp1 + k * 4);
      }
      // out rows from h2_{t-1}; WG w owns p-slice [4w, 4w+4)
      if (lyr == 1 && t >= TSTEPS - 63 && (tid & 3) == (w >> 3))
        *(f32x4*)(out + (size_t)b * 8192 + (t - 1 - (TSTEPS - 64)) * 128 + w * 4) = hv4[w & 7];
#pragma unroll
      for (int k = 0; k < 8; ++k) {
        f16x4 h16;
#pragma unroll
        for (int e = 0; e < 4; ++e) h16[e] = (f16)hv4[k][e];
        *(f16x4*)(&h_lds[b][pb + k * 4]) = h16;
      }
      if (lyr == 1 && !tail) {
#pragma unroll
        for (int k = 0; k < 8; ++k) {
          f16x4 h16;
#pragma unroll
          for (int e = 0; e < 4; ++e) h16[e] = (f16)x1v[k][e];
          *(f16x4*)(&x1_lds[b][pb + k * 4]) = h16;
        }
      }
      // zero our p-slice [4w,4w+4) of slot t+4 (holds h[t-4]; reads done
      // under the f1>=t-3 / own>=t throttles -- audited r8/r9/r11/r12)
      if (!tail)
        ast32f(myacc + (size_t)((t + 4) & 7) * 8192 + b * 128 + w * 4 + (tid & 3), 0.f);
    }
    if (tail) break;   // uniform for all l1 threads
    __syncthreads();

    // ================= gates: recurrent part (+ l1 input part) =============
#pragma unroll
    for (int mtl = 0; mtl < 2; ++mtl) {
#pragma unroll
      for (int ks = 0; ks < 4; ++ks) {
        f16x8 af = *(const f16x8*)(&h_lds[(wy * 2 + mtl) * 16 + l15][ks * 32 + lg * 8]);
#pragma unroll
        for (int ntl = 0; ntl < 4; ++ntl)
          acc[mtl][ntl] = __builtin_amdgcn_mfma_f32_16x16x32_f16(af, bf[ks][ntl], acc[mtl][ntl], 0, 0, 0);
      }
      if (lyr == 1) {
#pragma unroll
        for (int ks2 = 0; ks2 < 4; ++ks2) {
          f16x8 xf = *(const f16x8*)(&x1_lds[(wy * 2 + mtl) * 16 + l15][ks2 * 32 + lg * 8]);
#pragma unroll
          for (int ntl = 0; ntl < 4; ++ntl)
            acc[mtl][ntl] = __builtin_amdgcn_mfma_f32_16x16x32_f16(xf, bf[4 + ks2][ntl], acc[mtl][ntl], 0, 0, 0);
        }
      }
      // elementwise: ntl = gate type (i,f,g,o) for unit wx*16+l15
#pragma unroll
      for (int r = 0; r < 4; ++r) {
        float gi = acc[mtl][0][r], gf = acc[mtl][1][r];
        float gg = acc[mtl][2][r], go = acc[mtl][3][r];
        float cc = sigm(gf) * c[mtl][r] + sigm(gi) * tanh_(gg);
        c[mtl][r] = cc;
        float s = sigm(go) * tanh_(cc);
        s_lds[(wy * 2 + mtl) * 16 + lg * 4 + r][wx * 16 + l15] = (f16)s;
      }
    }
    __syncthreads();

    // ================= proj [64,32]x[32,128] + atomic-add accumulate =======
    {
      float* dst = myacc + (size_t)(t & 7) * 8192;
#pragma unroll
      for (int pml = 0; pml < 2; ++pml) {
        f16x8 ap = *(const f16x8*)(&s_lds[(wy * 2 + pml) * 16 + l15][lg * 8]);
#pragma unroll
        for (int pnl = 0; pnl < 4; ++pnl) {
          f32x4 z = {0.f, 0.f, 0.f, 0.f};
          f32x4 pa = __builtin_amdgcn_mfma_f32_16x16x32_f16(ap, wf[pnl], z, 0, 0, 0);
          const int p = (pnl * 2 + wx) * 16 + l15;
#pragma unroll
          for (int r = 0; r < 4; ++r) {
            const int b = (wy * 2 + pml) * 16 + lg * 4 + r;
            aadd_f32(dst + b * 128 + p, pa[r]);
          }
        }
      }
    }
    vm_drain();        // adds + zero stores acked at MALL
    __syncthreads();   // all waves drained
    if (tid == 0) ast32u(myf + w, (unsigned)(t + 1));
  }

  if (tmo && tid == 0) out[0] = 12345.0f;  // livelock canary
}

extern "C" void kernel_launch(void* const* d_in, const int* in_sizes, int n_in,
                              void* d_out, int out_size, void* d_ws, size_t ws_size,
                              hipStream_t stream)
{
  const float* x    = (const float*)d_in[0];
  const float* Wih0 = (const float*)d_in[1];
  const float* Whh0 = (const float*)d_in[2];
  const float* bih0 = (const float*)d_in[3];
  const float* bhh0 = (const float*)d_in[4];
  const float* Whr0 = (const float*)d_in[5];
  const float* Wih1 = (const float*)d_in[6];
  const float* Whh1 = (const float*)d_in[7];
  const float* bih1 = (const float*)d_in[8];
  const float* bhh1 = (const float*)d_in[9];
  const float* Whr1 = (const float*)d_in[10];

  if (ws_size < WS_NEED) return;

  char* ws = (char*)d_ws;
  f16*      Bsw   = (f16*)(ws + BSW_OFF);
  f16*      Whrsw = (f16*)(ws + WHR_OFF);
  float*    bias  = (float*)(ws + BIAS_OFF);
  float*    hacc  = (float*)(ws + HACC_OFF);
  unsigned* flags = (unsigned*)(ws + FLAG_OFF);

  lstm_setup<<<130, 256, 0, stream>>>(Wih0, Whh0, bih0, bhh0, Whr0,
                                      Wih1, Whh1, bih1, bhh1, Whr1,
                                      Bsw, Whrsw, bias, hacc, flags);
  lstm_main<<<64, 256, 0, stream>>>(x, (float*)d_out, Bsw, Whrsw, bias,
                                    hacc, flags);
}

// Round 15
// 17041.338 us; speedup vs baseline: 1.2949x; 1.0097x over previous
//
#include <hip/hip_runtime.h>
#include <hip/hip_fp16.h>

// ============================================================================
// 2-layer LSTM with projection (proj_size=128, H=1024, B=64, T=2048)
//
// Round 15 = round 13 RESUBMITTED UNCHANGED, third attempt (rounds 13 & 14
// were infra flakes: container died before the kernel was pushed; 5 flakes
// total this session, all pre-push, all the same pod).
// Round 13 design = round 12 (17.2 ms, best) + BUSY-SPIN polls (no s_sleep).
// Rationale: r5/r7/r9/r12 structural changes all bounce off an ~8 us/step
// floor; 8.4 us at 2.4 GHz = 20K cycles -- implausible for a ~6K-cycle chain.
// VALUBusy 2.7% + s_sleep-dominated waves => power governor likely holds
// SCLK low (~800 MHz), inflating every chain latency ~2.5x. Busy-spinning
// the flag polls keeps issue pipes busy (clocks up) and cuts discovery
// latency (sample period = load RT). Timeout check every 64th iteration
// (exit is wave-uniform; post-timeout all waits trip -> uniform drain,
// barriers stay matched). Everything else byte-identical to round 12:
//  - 32 WGs/layer x 256 thr, register-resident f16 weights (r7 packing).
//  - Per-WG flag stores f0[32]/f1[32]; all 4 waves poll independently.
//  - l0 x-GEMM hoisted pre-poll; batched h/h1 load issue.
//  - Atomic-add h-accumulation, 8-deep slot ring, zero slot t+4 at step t.
//  - Relaxed AGENT atomics (sc1) everywhere; no cache maintenance.
// Throttles: l0 step t: own f0>=t, f1>=t-3. l1 step t: f0>=t+1, own f1>=t.
// ============================================================================

typedef _Float16 f16;
typedef _Float16 f16x4 __attribute__((ext_vector_type(4)));
typedef _Float16 f16x8 __attribute__((ext_vector_type(8)));
typedef float f32x4 __attribute__((ext_vector_type(4)));
typedef unsigned long long u64;
struct U128 { u64 lo, hi; };

#define TSTEPS 2048
#define NW 32
#define TIMEOUT_TICKS 200000000ull   // ~2 s at 100 MHz s_memrealtime

// ---- workspace layout (bytes) ----
#define BSW_OFF  0ull
#define BSW_SZ   (64ull*32768ull*2ull)        // gate weights, 4 MiB
#define WHR_OFF  (BSW_OFF + BSW_SZ)
#define WHR_SZ   (64ull*4096ull*2ull)         // proj weights, 512 KiB
#define BIAS_OFF (WHR_OFF + WHR_SZ)
#define BIAS_SZ  (8192ull*4ull)
#define HACC_OFF (BIAS_OFF + BIAS_SZ)
#define HACC_SZ  (2ull*8ull*8192ull*4ull)     // [lyr][slot8][64b x 128p] f32
#define FLAG_OFF (HACC_OFF + HACC_SZ)
#define FLAG_SZ  (512ull)                     // f0[32] @0, f1[32] @128B
#define WS_NEED  (FLAG_OFF + FLAG_SZ)

__device__ __forceinline__ float sigm(float v) {
  float e = __builtin_amdgcn_exp2f(-1.4426950408889634f * v);
  return __builtin_amdgcn_rcpf(1.0f + e);
}
__device__ __forceinline__ float tanh_(float v) {
  float a = fabsf(v);
  float e = __builtin_amdgcn_exp2f(-2.8853900817779268f * a);
  float r = (1.0f - e) * __builtin_amdgcn_rcpf(1.0f + e);
  return copysignf(r, v);
}

// ---- relaxed agent-scope atomic helpers (compile to global_* sc1) --------
__device__ __forceinline__ u64 ald64(const void* p) {
  return __hip_atomic_load((const u64*)p, __ATOMIC_RELAXED, __HIP_MEMORY_SCOPE_AGENT);
}
__device__ __forceinline__ unsigned ald32u(const unsigned* p) {
  return __hip_atomic_load(p, __ATOMIC_RELAXED, __HIP_MEMORY_SCOPE_AGENT);
}
__device__ __forceinline__ void ast32f(float* p, float v) {
  __hip_atomic_store((unsigned*)p, __builtin_bit_cast(unsigned, v),
                     __ATOMIC_RELAXED, __HIP_MEMORY_SCOPE_AGENT);
}
__device__ __forceinline__ void ast32u(unsigned* p, unsigned v) {
  __hip_atomic_store(p, v, __ATOMIC_RELAXED, __HIP_MEMORY_SCOPE_AGENT);
}
__device__ __forceinline__ f32x4 ald_f32x4(const float* p) {
  U128 u; u.lo = ald64(p); u.hi = ald64(p + 2);
  return __builtin_bit_cast(f32x4, u);
}
__device__ __forceinline__ void aadd_f32(float* p, float v) {
  (void)__hip_atomic_fetch_add(p, v, __ATOMIC_RELAXED, __HIP_MEMORY_SCOPE_AGENT);
}
__device__ __forceinline__ void vm_drain() {
  asm volatile("s_waitcnt vmcnt(0)" ::: "memory");
}

// ---------------------------------------------------------------------------
// Setup (round-7 weight packing, proven). Fragment conventions (16x16x32):
//   A-frag: lane l holds A[m=l&15][k=(l>>4)*8+i]
//   B-frag: lane l holds B[k=(l>>4)*8+i][n=l&15]
//   D:      lane l, reg r -> D[m=(l>>4)*4+r][n=l&15]
// ---------------------------------------------------------------------------
__global__ void lstm_setup(
    const float* __restrict__ Wih0, const float* __restrict__ Whh0,
    const float* __restrict__ bih0, const float* __restrict__ bhh0,
    const float* __restrict__ Whr0,
    const float* __restrict__ Wih1, const float* __restrict__ Whh1,
    const float* __restrict__ bih1, const float* __restrict__ bhh1,
    const float* __restrict__ Whr1,
    f16* __restrict__ Bsw, f16* __restrict__ Whrsw, float* __restrict__ bias,
    float* __restrict__ hacc, unsigned* __restrict__ flags)
{
  const int blk = blockIdx.x, tid = threadIdx.x;
  if (blk < 64) {
    const int lyr = blk >> 5, w = blk & 31;
    const float* Whh = lyr ? Whh1 : Whh0;
    const float* Wih = lyr ? Wih1 : Wih0;
    f16* dst = Bsw + (size_t)blk * 32768;
    for (int e = tid; e < 32768; e += 256) {
      int i = e & 7, l = (e >> 3) & 63, ntG = (e >> 9) & 7, ks = e >> 12;
      int k  = ks * 32 + (l >> 4) * 8 + i;
      int rl = ntG * 16 + (l & 15);
      int grow = (rl >> 5) * 1024 + w * 32 + (rl & 31);
      float v = (k < 128) ? Whh[grow * 128 + k] : Wih[grow * 128 + (k - 128)];
      dst[e] = (f16)v;
    }
  } else if (blk < 128) {
    const int q = blk - 64, lyr = q >> 5, w = q & 31;
    const float* Whr = lyr ? Whr1 : Whr0;
    f16* dst = Whrsw + (size_t)q * 4096;
    for (int e = tid; e < 4096; e += 256) {
      int i = e & 7, l = (e >> 3) & 63, pnG = e >> 9;
      int p = pnG * 16 + (l & 15);
      int hg = w * 32 + (l >> 4) * 8 + i;
      dst[e] = (f16)Whr[p * 1024 + hg];
    }
  } else if (blk == 128) {
    for (int e = tid; e < 8192; e += 256) {
      int lyr = e >> 12, j = e & 4095;
      bias[e] = lyr ? (bih1[j] + bhh1[j]) : (bih0[j] + bhh0[j]);
    }
  } else {
    for (int e = tid; e < 2 * 8 * 8192; e += 256) ast32f(hacc + e, 0.f);
    if (tid < 128) ast32u(flags + tid, 0u);
  }
}

// ---------------------------------------------------------------------------
// Main persistent kernel: 64 WGs x 256 thr (4 waves, (wy,wx) 2x2; r7 wave
// mapping: gate M-tiles {wy*2,wy*2+1}, gate N-tiles {ntl*2+wx} (ntl = gate
// type); proj P-tiles {pnl*2+wx}).
// ---------------------------------------------------------------------------
__global__ __launch_bounds__(256, 1) void lstm_main(
    const float* __restrict__ x, float* __restrict__ out,
    const f16* __restrict__ Bsw, const f16* __restrict__ Whrsw,
    const float* __restrict__ bias, float* __restrict__ hacc,
    unsigned* __restrict__ flags)
{
  const int tid = threadIdx.x;
  const int lane = tid & 63, wv = tid >> 6;
  const int wy = wv >> 1, wx = wv & 1;
  const int l15 = lane & 15, lg = lane >> 4;
  const int w = blockIdx.x & 31, lyr = blockIdx.x >> 5;

  const u64 tstart = __builtin_amdgcn_s_memrealtime();
  bool tmo = false;

  __shared__ __align__(16) f16 h_lds[64][136];   // h_{t-1}, row=batch, col=p
  __shared__ __align__(16) f16 x1_lds[64][136];  // l1: h1_t
  __shared__ __align__(16) f16 s_lds[64][40];    // s, row=batch, 32 cols used

  // ---- register-resident weights (r7 packing) ----
  f16x8 bf[8][4];
  {
    const f16* bsl = Bsw + (size_t)(lyr * NW + w) * 32768;
#pragma unroll
    for (int ks = 0; ks < 8; ++ks)
#pragma unroll
      for (int ntl = 0; ntl < 4; ++ntl)
        bf[ks][ntl] = *(const f16x8*)(bsl + (((ks * 8 + (ntl * 2 + wx)) * 64 + lane) * 8));
  }
  f16x8 wf[4];
  {
    const f16* wsl = Whrsw + (size_t)(lyr * NW + w) * 4096;
#pragma unroll
    for (int pnl = 0; pnl < 4; ++pnl)
      wf[pnl] = *(const f16x8*)(wsl + (((pnl * 2 + wx) * 64 + lane) * 8));
  }
  float bias_r[4];
#pragma unroll
  for (int ntl = 0; ntl < 4; ++ntl)
    bias_r[ntl] = bias[lyr * 4096 + ntl * 1024 + w * 32 + wx * 16 + l15];

  float c[2][4] = {{0.f,0.f,0.f,0.f},{0.f,0.f,0.f,0.f}};

  unsigned* f0 = flags;        // [32]
  unsigned* f1 = flags + 32;   // [32]
  unsigned* myf = lyr ? f1 : f0;
  float* myacc = hacc + (size_t)lyr * 8 * 8192;
  float* h1a   = hacc;
  __syncthreads();

  for (int t = 0; t <= TSTEPS; ++t) {
    if (lyr == 0 && t == TSTEPS) break;
    const bool tail = (t == TSTEPS);             // l1 only

    // ---- pre-poll: bias init + (l0) x-part of gate GEMM (K=128..255) ------
    f32x4 acc[2][4];
#pragma unroll
    for (int mtl = 0; mtl < 2; ++mtl)
#pragma unroll
      for (int ntl = 0; ntl < 4; ++ntl) {
        f32x4 b4 = {bias_r[ntl], bias_r[ntl], bias_r[ntl], bias_r[ntl]};
        acc[mtl][ntl] = b4;
      }
    if (lyr == 0) {
#pragma unroll
      for (int mtl = 0; mtl < 2; ++mtl) {
        const float* xp = x + ((size_t)((wy * 2 + mtl) * 16 + l15) * TSTEPS + t) * 128 + lg * 8;
#pragma unroll
        for (int ks2 = 0; ks2 < 4; ++ks2) {
          f32x4 v0 = *(const f32x4*)(xp + ks2 * 32);
          f32x4 v1 = *(const f32x4*)(xp + ks2 * 32 + 4);
          f16x8 hx;
          hx[0]=(f16)v0[0]; hx[1]=(f16)v0[1]; hx[2]=(f16)v0[2]; hx[3]=(f16)v0[3];
          hx[4]=(f16)v1[0]; hx[5]=(f16)v1[1]; hx[6]=(f16)v1[2]; hx[7]=(f16)v1[3];
#pragma unroll
          for (int ntl = 0; ntl < 4; ++ntl)
            acc[mtl][ntl] = __builtin_amdgcn_mfma_f32_16x16x32_f16(hx, bf[4 + ks2][ntl], acc[mtl][ntl], 0, 0, 0);
        }
      }
    }

    // ========== poll: BUSY-SPIN, all waves independently ==========
    // No s_sleep: keeps issue pipes busy (DPM holds clocks up) and makes
    // the sample period = one load RT. Timeout checked every 64 iters.
    {
      int itc = 0;
      for (;;) {
        bool ok = true;
        if (lane < 32) {
          ok = ald32u(myf + lane) >= (unsigned)t;                     // own layer
        } else {
          const int l2 = lane - 32;
          if (lyr == 0) ok = (t < 4) || (ald32u(f1 + l2) >= (unsigned)(t - 3));
          else          ok = tail || (ald32u(f0 + l2) >= (unsigned)(t + 1));
        }
        if (__all(ok)) break;
        if ((++itc & 63) == 0) {
          if ((__builtin_amdgcn_s_memrealtime() - tstart) > TIMEOUT_TICKS) { tmo = true; break; }
        }
      }
    }
    asm volatile("" ::: "memory");

    // ================= read: issue ALL loads, then convert =================
    {
      const int b = tid >> 2, pb = (tid & 3) * 32;       // 32 f32 per thread
      const float* hp = myacc + (size_t)((t + 7) & 7) * 8192 + b * 128 + pb;
      f32x4 hv4[8];
#pragma unroll
      for (int k = 0; k < 8; ++k) hv4[k] = ald_f32x4(hp + k * 4);
      f32x4 x1v[8];
      if (lyr == 1 && !tail) {
        const float* xp1 = h1a + (size_t)(t & 7) * 8192 + b * 128 + pb;
#pragma unroll
        for (int k = 0; k < 8; ++k) x1v[k] = ald_f32x4(xp1 + k * 4);
      }
      // out rows from h2_{t-1}; WG w owns p-slice [4w, 4w+4)
      if (lyr == 1 && t >= TSTEPS - 63 && (tid & 3) == (w >> 3))
        *(f32x4*)(out + (size_t)b * 8192 + (t - 1 - (TSTEPS - 64)) * 128 + w * 4) = hv4[w & 7];
#pragma unroll
      for (int k = 0; k < 8; ++k) {
        f16x4 h16;
#pragma unroll
        for (int e = 0; e < 4; ++e) h16[e] = (f16)hv4[k][e];
        *(f16x4*)(&h_lds[b][pb + k * 4]) = h16;
      }
      if (lyr == 1 && !tail) {
#pragma unroll
        for (int k = 0; k < 8; ++k) {
          f16x4 h16;
#pragma unroll
          for (int e = 0; e < 4; ++e) h16[e] = (f16)x1v[k][e];
          *(f16x4*)(&x1_lds[b][pb + k * 4]) = h16;
        }
      }
      // zero our p-slice [4w,4w+4) of slot t+4 (holds h[t-4]; reads done
      // under the f1>=t-3 / own>=t throttles -- audited r8/r9/r11/r12)
      if (!tail)
        ast32f(myacc + (size_t)((t + 4) & 7) * 8192 + b * 128 + w * 4 + (tid & 3), 0.f);
    }
    if (tail) break;   // uniform for all l1 threads
    __syncthreads();

    // ================= gates: recurrent part (+ l1 input part) =============
#pragma unroll
    for (int mtl = 0; mtl < 2; ++mtl) {
#pragma unroll
      for (int ks = 0; ks < 4; ++ks) {
        f16x8 af = *(const f16x8*)(&h_lds[(wy * 2 + mtl) * 16 + l15][ks * 32 + lg * 8]);
#pragma unroll
        for (int ntl = 0; ntl < 4; ++ntl)
          acc[mtl][ntl] = __builtin_amdgcn_mfma_f32_16x16x32_f16(af, bf[ks][ntl], acc[mtl][ntl], 0, 0, 0);
      }
      if (lyr == 1) {
#pragma unroll
        for (int ks2 = 0; ks2 < 4; ++ks2) {
          f16x8 xf = *(const f16x8*)(&x1_lds[(wy * 2 + mtl) * 16 + l15][ks2 * 32 + lg * 8]);
#pragma unroll
          for (int ntl = 0; ntl < 4; ++ntl)
            acc[mtl][ntl] = __builtin_amdgcn_mfma_f32_16x16x32_f16(xf, bf[4 + ks2][ntl], acc[mtl][ntl], 0, 0, 0);
        }
      }
      // elementwise: ntl = gate type (i,f,g,o) for unit wx*16+l15
#pragma unroll
      for (int r = 0; r < 4; ++r) {
        float gi = acc[mtl][0][r], gf = acc[mtl][1][r];
        float gg = acc[mtl][2][r], go = acc[mtl][3][r];
        float cc = sigm(gf) * c[mtl][r] + sigm(gi) * tanh_(gg);
        c[mtl][r] = cc;
        float s = sigm(go) * tanh_(cc);
        s_lds[(wy * 2 + mtl) * 16 + lg * 4 + r][wx * 16 + l15] = (f16)s;
      }
    }
    __syncthreads();

    // ================= proj [64,32]x[32,128] + atomic-add accumulate =======
    {
      float* dst = myacc + (size_t)(t & 7) * 8192;
#pragma unroll
      for (int pml = 0; pml < 2; ++pml) {
        f16x8 ap = *(const f16x8*)(&s_lds[(wy * 2 + pml) * 16 + l15][lg * 8]);
#pragma unroll
        for (int pnl = 0; pnl < 4; ++pnl) {
          f32x4 z = {0.f, 0.f, 0.f, 0.f};
          f32x4 pa = __builtin_amdgcn_mfma_f32_16x16x32_f16(ap, wf[pnl], z, 0, 0, 0);
          const int p = (pnl * 2 + wx) * 16 + l15;
#pragma unroll
          for (int r = 0; r < 4; ++r) {
            const int b = (wy * 2 + pml) * 16 + lg * 4 + r;
            aadd_f32(dst + b * 128 + p, pa[r]);
          }
        }
      }
    }
    vm_drain();        // adds + zero stores acked at MALL
    __syncthreads();   // all waves drained
    if (tid == 0) ast32u(myf + w, (unsigned)(t + 1));
  }

  if (tmo && tid == 0) out[0] = 12345.0f;  // livelock canary
}

extern "C" void kernel_launch(void* const* d_in, const int* in_sizes, int n_in,
                              void* d_out, int out_size, void* d_ws, size_t ws_size,
                              hipStream_t stream)
{
  const float* x    = (const float*)d_in[0];
  const float* Wih0 = (const float*)d_in[1];
  const float* Whh0 = (const float*)d_in[2];
  const float* bih0 = (const float*)d_in[3];
  const float* bhh0 = (const float*)d_in[4];
  const float* Whr0 = (const float*)d_in[5];
  const float* Wih1 = (const float*)d_in[6];
  const float* Whh1 = (const float*)d_in[7];
  const float* bih1 = (const float*)d_in[8];
  const float* bhh1 = (const float*)d_in[9];
  const float* Whr1 = (const float*)d_in[10];

  if (ws_size < WS_NEED) return;

  char* ws = (char*)d_ws;
  f16*      Bsw   = (f16*)(ws + BSW_OFF);
  f16*      Whrsw = (f16*)(ws + WHR_OFF);
  float*    bias  = (float*)(ws + BIAS_OFF);
  float*    hacc  = (float*)(ws + HACC_OFF);
  unsigned* flags = (unsigned*)(ws + FLAG_OFF);

  lstm_setup<<<130, 256, 0, stream>>>(Wih0, Whh0, bih0, bhh0, Whr0,
                                      Wih1, Whh1, bih1, bhh1, Whr1,
                                      Bsw, Whrsw, bias, hacc, flags);
  lstm_main<<<64, 256, 0, stream>>>(x, (float*)d_out, Bsw, Whrsw, bias,
                                    hacc, flags);
}